// Round 2
// baseline (1777.898 us; speedup 1.0000x reference)
//
#include <hip/hip_runtime.h>

typedef unsigned short u16;
typedef __attribute__((ext_vector_type(8))) short bf16x8;
typedef __attribute__((ext_vector_type(4))) float f32x4;

__device__ __forceinline__ u16 f2bf(float f) {
  unsigned u = __float_as_uint(f);
  return (u16)((u + 0x7fffu + ((u >> 16) & 1u)) >> 16);
}
__device__ __forceinline__ float bf2f(u16 v) { return __uint_as_float(((unsigned)v) << 16); }
__device__ __forceinline__ float sigm(float x) { return 1.f / (1.f + __expf(-x)); }
__device__ __forceinline__ float tanh_(float x) {
  x = fminf(fmaxf(x, -15.f), 15.f);
  float e = __expf(2.f * x);
  return (e - 1.f) / (e + 1.f);
}

// ---------------- weight fp32 -> bf16 conversion (hi, optional lo residual) -------------
// segments (2048 elems/blk): w_embed 128 blks (hi+lo), w_ih_f 384 (hi+lo), w_hh_f 384 (hi),
//                            w_ih_b 384 (hi+lo), w_hh_b 384 (hi), att_w1 128 (hi)
__global__ __launch_bounds__(256) void k_convert(
    const float* __restrict__ s0, const float* __restrict__ s1, const float* __restrict__ s2,
    const float* __restrict__ s3, const float* __restrict__ s4, const float* __restrict__ s5,
    u16* __restrict__ h0, u16* __restrict__ l0,
    u16* __restrict__ h1, u16* __restrict__ l1,
    u16* __restrict__ h2,
    u16* __restrict__ h3, u16* __restrict__ l3,
    u16* __restrict__ h4,
    u16* __restrict__ h5) {
  int blk = blockIdx.x;
  const float* s; u16 *dh, *dl; int rel;
  if (blk < 128)       { s = s0; dh = h0; dl = l0;      rel = blk; }
  else if (blk < 512)  { s = s1; dh = h1; dl = l1;      rel = blk - 128; }
  else if (blk < 896)  { s = s2; dh = h2; dl = nullptr; rel = blk - 512; }
  else if (blk < 1280) { s = s3; dh = h3; dl = l3;      rel = blk - 896; }
  else if (blk < 1664) { s = s4; dh = h4; dl = nullptr; rel = blk - 1280; }
  else                 { s = s5; dh = h5; dl = nullptr; rel = blk - 1664; }
  size_t i = (size_t)rel * 2048 + (size_t)threadIdx.x * 8;
  float v[8];
  *(f32x4*)v = *(const f32x4*)(s + i);
  *(f32x4*)(v + 4) = *(const f32x4*)(s + i + 4);
  u16 oh[8], ol[8];
#pragma unroll
  for (int j = 0; j < 8; j++) {
    oh[j] = f2bf(v[j]);
    ol[j] = f2bf(v[j] - bf2f(oh[j]));
  }
  uint4 pk;
  pk.x = (unsigned)oh[0] | ((unsigned)oh[1] << 16);
  pk.y = (unsigned)oh[2] | ((unsigned)oh[3] << 16);
  pk.z = (unsigned)oh[4] | ((unsigned)oh[5] << 16);
  pk.w = (unsigned)oh[6] | ((unsigned)oh[7] << 16);
  *(uint4*)(dh + i) = pk;
  if (dl) {
    uint4 pl;
    pl.x = (unsigned)ol[0] | ((unsigned)ol[1] << 16);
    pl.y = (unsigned)ol[2] | ((unsigned)ol[3] << 16);
    pl.z = (unsigned)ol[4] | ((unsigned)ol[5] << 16);
    pl.w = (unsigned)ol[6] | ((unsigned)ol[7] << 16);
    *(uint4*)(dl + i) = pl;
  }
}

// ---------------- fused conv + vec ----------------
// one WG per (b,s): stage [32][512] fp32 block in LDS (read inputs ONCE),
// conv[p] = dot(block[p,:], conv_w)+conv_b ; vec[d] = sum_p conv[p]*block[p][d]
// outputs vec split hi/lo bf16 (vec std ~7.4 -> single bf16 would cost 2e-2 downstream)
__global__ __launch_bounds__(256) void k_convvec(
    const float* __restrict__ x, const float* __restrict__ cw,
    const float* __restrict__ cb, u16* __restrict__ vh, u16* __restrict__ vl) {
  __shared__ float lx[32 * 512];
  __shared__ float lcw[512];
  __shared__ float lconv[32];
  int bs = blockIdx.x;  // b*64+s
  const float* xp = x + (size_t)bs * 32 * 512;
  int t = threadIdx.x;
#pragma unroll
  for (int i = 0; i < 16; i++) {
    int idx = t + i * 256;
    ((float4*)lx)[idx] = ((const float4*)xp)[idx];
  }
  if (t < 128) ((float4*)lcw)[t] = ((const float4*)cw)[t];
  __syncthreads();
  int p = t >> 3, l = t & 7;
  float acc = 0.f;
#pragma unroll 8
  for (int j = 0; j < 64; j++) {
    int d = l + 8 * j;
    acc += lx[p * 512 + d] * lcw[d];
  }
  acc += __shfl_down(acc, 4);
  acc += __shfl_down(acc, 2);
  acc += __shfl_down(acc, 1);
  if (l == 0) lconv[p] = acc + cb[0];
  __syncthreads();
#pragma unroll
  for (int i = 0; i < 2; i++) {
    int d = t + i * 256;
    float v = 0.f;
#pragma unroll
    for (int pp = 0; pp < 32; pp++) v += lconv[pp] * lx[pp * 512 + d];
    u16 hb = f2bf(v);
    vh[(size_t)bs * 512 + d] = hb;
    vl[(size_t)bs * 512 + d] = f2bf(v - bf2f(hb));
  }
}

// ---------------- split-bf16 MFMA GEMM: C = act((Ah+Al)[M,K] @ (Wh+Wl)[N,K]^T + bias) ----
// acc = Ah*Wh + Al*Wh + Ah*Wl  (lo*lo dropped, ~2^-16 rel). Al/Wl may be null.
// flags: 1 = clip(-1,1), 2 = transpose output rows (m=b*64+s -> row s*64+b)
__global__ __launch_bounds__(256) void k_gemm(
    const u16* __restrict__ Ah, const u16* __restrict__ Al,
    const u16* __restrict__ Wh, const u16* __restrict__ Wl,
    const float* __restrict__ bias, float* __restrict__ outf,
    u16* __restrict__ obh, u16* __restrict__ obl,
    int M, int N, int K, int flags) {
  __shared__ u16 lAh[128 * 32];
  __shared__ u16 lAl[128 * 32];
  __shared__ u16 lWh[128 * 32];
  __shared__ u16 lWl[128 * 32];
  int m0 = blockIdx.x * 128, n0 = blockIdx.y * 128;
  int t = threadIdx.x;
  int wave = t >> 6, lane = t & 63;
  int wy = wave >> 1, wx = wave & 1;
  int q = lane >> 4, r16 = lane & 15;
  f32x4 acc[4][4];
#pragma unroll
  for (int mi = 0; mi < 4; mi++)
#pragma unroll
    for (int ni = 0; ni < 4; ni++) acc[mi][ni] = (f32x4){0.f, 0.f, 0.f, 0.f};

  for (int k0 = 0; k0 < K; k0 += 32) {
    __syncthreads();
#pragma unroll
    for (int i = 0; i < 2; i++) {
      int c = t + i * 256;
      int row = c >> 2, seg = c & 3;
      int lo = row * 32 + seg * 8;
      size_t ga = (size_t)(m0 + row) * K + k0 + seg * 8;
      size_t gw = (size_t)(n0 + row) * K + k0 + seg * 8;
      *(uint4*)(&lAh[lo]) = *(const uint4*)(&Ah[ga]);
      *(uint4*)(&lWh[lo]) = *(const uint4*)(&Wh[gw]);
      if (Al) *(uint4*)(&lAl[lo]) = *(const uint4*)(&Al[ga]);
      if (Wl) *(uint4*)(&lWl[lo]) = *(const uint4*)(&Wl[gw]);
    }
    __syncthreads();
    bf16x8 afh[4], bfh[4], afl[4], bfl[4];
#pragma unroll
    for (int mi = 0; mi < 4; mi++) afh[mi] = *(bf16x8*)(&lAh[(wy * 64 + mi * 16 + r16) * 32 + q * 8]);
#pragma unroll
    for (int ni = 0; ni < 4; ni++) bfh[ni] = *(bf16x8*)(&lWh[(wx * 64 + ni * 16 + r16) * 32 + q * 8]);
    if (Al) {
#pragma unroll
      for (int mi = 0; mi < 4; mi++) afl[mi] = *(bf16x8*)(&lAl[(wy * 64 + mi * 16 + r16) * 32 + q * 8]);
    }
    if (Wl) {
#pragma unroll
      for (int ni = 0; ni < 4; ni++) bfl[ni] = *(bf16x8*)(&lWl[(wx * 64 + ni * 16 + r16) * 32 + q * 8]);
    }
#pragma unroll
    for (int mi = 0; mi < 4; mi++)
#pragma unroll
      for (int ni = 0; ni < 4; ni++)
        acc[mi][ni] = __builtin_amdgcn_mfma_f32_16x16x32_bf16(afh[mi], bfh[ni], acc[mi][ni], 0, 0, 0);
    if (Al) {
#pragma unroll
      for (int mi = 0; mi < 4; mi++)
#pragma unroll
        for (int ni = 0; ni < 4; ni++)
          acc[mi][ni] = __builtin_amdgcn_mfma_f32_16x16x32_bf16(afl[mi], bfh[ni], acc[mi][ni], 0, 0, 0);
    }
    if (Wl) {
#pragma unroll
      for (int mi = 0; mi < 4; mi++)
#pragma unroll
        for (int ni = 0; ni < 4; ni++)
          acc[mi][ni] = __builtin_amdgcn_mfma_f32_16x16x32_bf16(afh[mi], bfl[ni], acc[mi][ni], 0, 0, 0);
    }
  }
#pragma unroll
  for (int mi = 0; mi < 4; mi++)
#pragma unroll
    for (int ni = 0; ni < 4; ni++)
#pragma unroll
      for (int reg = 0; reg < 4; reg++) {
        int m = m0 + wy * 64 + mi * 16 + q * 4 + reg;
        int n = n0 + wx * 64 + ni * 16 + r16;
        float v = acc[mi][ni][reg];
        if (bias) v += bias[n];
        if (flags & 1) v = fminf(fmaxf(v, -1.f), 1.f);
        int mr = (flags & 2) ? ((m & 63) * 64 + (m >> 6)) : m;
        size_t o = (size_t)mr * N + n;
        if (outf) outf[o] = v;
        if (obh) {
          u16 hb = f2bf(v);
          obh[o] = hb;
          if (obl) obl[o] = f2bf(v - bf2f(hb));
        }
      }
}

// ---------------- GRU recurrence (both directions, persistent, grid barrier) -------------
__device__ __forceinline__ void grid_barrier(unsigned* cnt, unsigned* gen, unsigned nwg) {
  __builtin_amdgcn_fence(__ATOMIC_RELEASE, "agent");
  __syncthreads();
  if (threadIdx.x == 0) {
    unsigned g = __hip_atomic_load(gen, __ATOMIC_RELAXED, __HIP_MEMORY_SCOPE_AGENT);
    unsigned arrived = __hip_atomic_fetch_add(cnt, 1u, __ATOMIC_ACQ_REL, __HIP_MEMORY_SCOPE_AGENT);
    if (arrived == nwg - 1u) {
      __hip_atomic_store(cnt, 0u, __ATOMIC_RELAXED, __HIP_MEMORY_SCOPE_AGENT);
      __hip_atomic_fetch_add(gen, 1u, __ATOMIC_RELEASE, __HIP_MEMORY_SCOPE_AGENT);
    } else {
      while (__hip_atomic_load(gen, __ATOMIC_ACQUIRE, __HIP_MEMORY_SCOPE_AGENT) == g) {
        __builtin_amdgcn_s_sleep(1);
      }
    }
  }
  __syncthreads();
  __builtin_amdgcn_fence(__ATOMIC_ACQUIRE, "agent");
}

// 64 WGs: wg>>5 = dir, wg&31 = 16-row slice of H. w_hh slice lives in VGPRs as
// pre-built MFMA A-fragments (3 gates x 16 ktiles). h exchanged via L2, double-buffered.
__global__ __launch_bounds__(256, 1) void k_gru(
    const u16* __restrict__ whh_f, const u16* __restrict__ whh_b,
    const float* __restrict__ bhh_f, const float* __restrict__ bhh_b,
    const float* __restrict__ xg_f, const float* __restrict__ xg_b,
    u16* __restrict__ hbuf,            // [dir][2][64][512] bf16
    float* __restrict__ states_f32,    // d_out states region [b][s][1024]
    u16* __restrict__ states_bf,       // ws bf16 copy, same layout
    unsigned* bar_cnt, unsigned* bar_gen) {
  int wg = blockIdx.x;
  int dir = wg >> 5;
  int r0 = (wg & 31) * 16;
  int t = threadIdx.x, wave = t >> 6, lane = t & 63;
  int q = lane >> 4, r16 = lane & 15;
  const u16* whh = dir ? whh_b : whh_f;
  const float* bhh = dir ? bhh_b : bhh_f;
  const float* xg = dir ? xg_b : xg_f;

  // persistent weight fragments: wA[g][kt] : A[m=lane&15 -> row r0+m of gate g][k]
  bf16x8 wA[3][16];
#pragma unroll
  for (int g = 0; g < 3; g++)
#pragma unroll
    for (int kt = 0; kt < 16; kt++)
      wA[g][kt] = *(const bf16x8*)(&whh[(size_t)(g * 512 + r0 + r16) * 512 + kt * 32 + q * 8]);

  f32x4 bh[3];
#pragma unroll
  for (int g = 0; g < 3; g++) bh[g] = *(const f32x4*)(&bhh[g * 512 + r0 + q * 4]);

  float hreg[4] = {0.f, 0.f, 0.f, 0.f};
  int b = wave * 16 + r16;  // this lane's batch column (n = lane&15 in both B and D layouts)
  int cur = 0;

  for (int tt = 0; tt < 64; tt++) {
    int s = dir ? (63 - tt) : tt;
    // xg loads are h-independent: issue first so they overlap the MFMAs
    const float* xgp = xg + ((size_t)s * 64 + b) * 1536 + r0 + q * 4;
    f32x4 xr4 = *(const f32x4*)(xgp);
    f32x4 xz4 = *(const f32x4*)(xgp + 512);
    f32x4 xn4 = *(const f32x4*)(xgp + 1024);

    const u16* hc = hbuf + ((size_t)(dir * 2 + cur) * 64 + b) * 512;
    bf16x8 hfr[16];
#pragma unroll
    for (int kt = 0; kt < 16; kt++) hfr[kt] = *(const bf16x8*)(&hc[kt * 32 + q * 8]);

    f32x4 acc[3];
#pragma unroll
    for (int g = 0; g < 3; g++) acc[g] = (f32x4){0.f, 0.f, 0.f, 0.f};
#pragma unroll
    for (int kt = 0; kt < 16; kt++)
#pragma unroll
      for (int g = 0; g < 3; g++)
        acc[g] = __builtin_amdgcn_mfma_f32_16x16x32_bf16(wA[g][kt], hfr[kt], acc[g], 0, 0, 0);

    float hn4[4];
    u16 hnb[4];
#pragma unroll
    for (int reg = 0; reg < 4; reg++) {
      float hgr = acc[0][reg] + bh[0][reg];
      float hgz = acc[1][reg] + bh[1][reg];
      float hgn = acc[2][reg] + bh[2][reg];
      float rr = sigm(xr4[reg] + hgr);
      float zz = sigm(xz4[reg] + hgz);
      float nn = tanh_(xn4[reg] + rr * hgn);
      float hv = (1.f - zz) * nn + zz * hreg[reg];
      hreg[reg] = hv;
      hn4[reg] = hv;
      hnb[reg] = f2bf(hv);
    }
    int R = r0 + q * 4;
    float4 st; st.x = hn4[0]; st.y = hn4[1]; st.z = hn4[2]; st.w = hn4[3];
    *(float4*)(states_f32 + ((size_t)(b * 64 + s) * 1024 + dir * 512 + R)) = st;
    uint2 pk;
    pk.x = (unsigned)hnb[0] | ((unsigned)hnb[1] << 16);
    pk.y = (unsigned)hnb[2] | ((unsigned)hnb[3] << 16);
    *(uint2*)(states_bf + ((size_t)(b * 64 + s) * 1024 + dir * 512 + R)) = pk;
    *(uint2*)(hbuf + ((size_t)(dir * 2 + (cur ^ 1)) * 64 + b) * 512 + R) = pk;

    grid_barrier(bar_cnt, bar_gen, 64u);
    cur ^= 1;
  }
}

// ---------------- alpha = m1 @ att_w2^T ; softmax over S ----------------
__global__ __launch_bounds__(256) void k_alpha(
    const u16* __restrict__ m1, const float* __restrict__ w2,
    float* __restrict__ actv_out, float* __restrict__ actv_ws) {
  __shared__ float lw2[4 * 256];
  __shared__ float lal[256];
  __shared__ float red[8];
  int bb = blockIdx.x, t = threadIdx.x;
  for (int i = t; i < 1024; i += 256) lw2[i] = w2[i];
  __syncthreads();
  int s = t >> 2, h = t & 3;
  const u16* mp = m1 + ((size_t)bb * 64 + s) * 256;
  float a = 0.f;
  for (int c = 0; c < 256; c += 4) {
    ushort4 v = *(const ushort4*)(mp + c);
    a += bf2f(v.x) * lw2[h * 256 + c] + bf2f(v.y) * lw2[h * 256 + c + 1] +
         bf2f(v.z) * lw2[h * 256 + c + 2] + bf2f(v.w) * lw2[h * 256 + c + 3];
  }
  lal[s * 4 + h] = a;
  __syncthreads();
  if (t < 4) {
    float mx = -1e30f;
    for (int ss = 0; ss < 64; ss++) mx = fmaxf(mx, lal[ss * 4 + t]);
    float sm = 0.f;
    for (int ss = 0; ss < 64; ss++) sm += __expf(lal[ss * 4 + t] - mx);
    red[t] = mx; red[4 + t] = sm;
  }
  __syncthreads();
  float val = __expf(lal[s * 4 + h] - red[h]) / red[4 + h];
  int o = bb * 256 + h * 64 + s;
  actv_out[o] = val;
  actv_ws[o] = val;
}

// ---------------- context[b,h,:] = sum_s actv[b,h,s] * states[b,s,:] ----------------
__global__ __launch_bounds__(256) void k_context(
    const float* __restrict__ actv, const float* __restrict__ states, float* __restrict__ ctx) {
  __shared__ float la[64];
  int bb = blockIdx.x >> 2, h = blockIdx.x & 3, t = threadIdx.x;
  if (t < 64) la[t] = actv[bb * 256 + h * 64 + t];
  __syncthreads();
  const float* sp = states + (size_t)bb * 65536 + t * 4;
  f32x4 acc = (f32x4){0.f, 0.f, 0.f, 0.f};
  for (int s = 0; s < 64; s++) {
    f32x4 v = *(const f32x4*)(sp + (size_t)s * 1024);
    float a = la[s];
    acc += a * v;
  }
  *(f32x4*)(ctx + (size_t)bb * 4096 + h * 1024 + t * 4) = acc;
}

// ---------------- out = softmax(context @ lin_w^T + lin_b) ----------------
__global__ __launch_bounds__(256) void k_final(
    const float* __restrict__ ctx, const float* __restrict__ lw,
    const float* __restrict__ lb, float* __restrict__ out) {
  __shared__ float lctx[4096];
  __shared__ float lred[256];
  __shared__ float lout[16];
  int bb = blockIdx.x, t = threadIdx.x;
#pragma unroll
  for (int i = 0; i < 4; i++)
    ((float4*)lctx)[t + i * 256] = ((const float4*)(ctx + (size_t)bb * 4096))[t + i * 256];
  __syncthreads();
  int o = t >> 4, j = t & 15;
  const float* wp = lw + (size_t)o * 4096 + j * 256;
  const float* cp = lctx + j * 256;
  float a = 0.f;
  for (int c = 0; c < 256; c++) a += cp[c] * wp[c];
  lred[t] = a;
  __syncthreads();
  if (t < 16) {
    float v = lb[t];
    for (int jj = 0; jj < 16; jj++) v += lred[t * 16 + jj];
    lout[t] = v;
  }
  __syncthreads();
  if (t == 0) {
    float mx = -1e30f;
    for (int i = 0; i < 16; i++) mx = fmaxf(mx, lout[i]);
    float sm = 0.f;
    for (int i = 0; i < 16; i++) { float e = __expf(lout[i] - mx); lout[i] = e; sm += e; }
    float inv = 1.f / sm;
    for (int i = 0; i < 16; i++) out[bb * 16 + i] = lout[i] * inv;
  }
}

// ---------------- launch ----------------
extern "C" void kernel_launch(void* const* d_in, const int* in_sizes, int n_in,
                              void* d_out, int out_size, void* d_ws, size_t ws_size,
                              hipStream_t stream) {
  const float* x      = (const float*)d_in[0];
  const float* conv_w = (const float*)d_in[2];
  const float* conv_b = (const float*)d_in[3];
  const float* w_embed= (const float*)d_in[4];
  const float* w_ih_f = (const float*)d_in[5];
  const float* w_hh_f = (const float*)d_in[6];
  const float* b_ih_f = (const float*)d_in[7];
  const float* b_hh_f = (const float*)d_in[8];
  const float* w_ih_b = (const float*)d_in[9];
  const float* w_hh_b = (const float*)d_in[10];
  const float* b_ih_b = (const float*)d_in[11];
  const float* b_hh_b = (const float*)d_in[12];
  const float* att_w1 = (const float*)d_in[13];
  const float* att_w2 = (const float*)d_in[14];
  const float* lin_w  = (const float*)d_in[15];
  const float* lin_b  = (const float*)d_in[16];

  char* ws = (char*)d_ws;
  // ws layout (bytes); later-phase arrays alias dead earlier-phase regions
  const size_t o_bar    = 0;          // 1024
  const size_t o_hbuf   = 1024;       // 524288
  const size_t o_wembh  = 525312;     // 524288
  const size_t o_wembl  = 1049600;    // 524288
  const size_t o_wihfh  = 1573888;    // 1572864
  const size_t o_wihfl  = 3146752;    // 1572864
  const size_t o_whhf   = 4719616;    // 1572864
  const size_t o_wihbh  = 6292480;    // 1572864
  const size_t o_wihbl  = 7865344;    // 1572864
  const size_t o_whhb   = 9438208;    // 1572864
  const size_t o_watt1  = 11011072;   // 524288
  const size_t o_embh   = 11535360;   // 4194304 (dead after xg GEMMs)
  const size_t o_embl   = 15729664;   // 4194304 (dead after xg GEMMs)
  const size_t o_vech   = 19923968;   // 4194304 (dead after emb GEMM)
  const size_t o_vecl   = 24118272;   // 4194304 (dead after emb GEMM)
  const size_t o_xgf    = 19923968;   // 25165824 (aliases vec; dead after k_gru)
  const size_t o_xgb    = 45089792;   // 25165824
  const size_t o_sbf    = 11535360;   // 8388608 (aliases emb; written by k_gru)
  const size_t o_m1     = 19923968;   // 2097152 (aliases xgf head; after k_gru)
  const size_t o_actv   = 22021120;   // 65536

  float* out_probs  = (float*)d_out;            // [64,16]
  float* out_states = out_probs + 1024;         // [64,64,1024]
  float* out_ctx    = out_probs + 4195328;      // [64,4096]
  float* out_actv   = out_probs + 4457472;      // [64,4,64]

  // zero barrier + h buffers (ws is re-poisoned to 0xAA before every timed launch)
  hipMemsetAsync(ws + o_bar, 0, 525312, stream);

  k_convert<<<1792, 256, 0, stream>>>(
      w_embed, w_ih_f, w_hh_f, w_ih_b, w_hh_b, att_w1,
      (u16*)(ws + o_wembh), (u16*)(ws + o_wembl),
      (u16*)(ws + o_wihfh), (u16*)(ws + o_wihfl),
      (u16*)(ws + o_whhf),
      (u16*)(ws + o_wihbh), (u16*)(ws + o_wihbl),
      (u16*)(ws + o_whhb),
      (u16*)(ws + o_watt1));

  k_convvec<<<4096, 256, 0, stream>>>(x, conv_w, conv_b,
                                      (u16*)(ws + o_vech), (u16*)(ws + o_vecl));

  // emb = clip(vec @ w_embed^T), split-bf16 both operands, output hi/lo
  k_gemm<<<dim3(32, 4), 256, 0, stream>>>(
      (u16*)(ws + o_vech), (u16*)(ws + o_vecl),
      (u16*)(ws + o_wembh), (u16*)(ws + o_wembl),
      nullptr, nullptr, (u16*)(ws + o_embh), (u16*)(ws + o_embl),
      4096, 512, 512, 1);

  // xg = emb @ w_ih^T + b_ih, split-bf16, stored [s*64+b][1536] fp32
  k_gemm<<<dim3(32, 12), 256, 0, stream>>>(
      (u16*)(ws + o_embh), (u16*)(ws + o_embl),
      (u16*)(ws + o_wihfh), (u16*)(ws + o_wihfl),
      b_ih_f, (float*)(ws + o_xgf), nullptr, nullptr,
      4096, 1536, 512, 2);
  k_gemm<<<dim3(32, 12), 256, 0, stream>>>(
      (u16*)(ws + o_embh), (u16*)(ws + o_embl),
      (u16*)(ws + o_wihbh), (u16*)(ws + o_wihbl),
      b_ih_b, (float*)(ws + o_xgb), nullptr, nullptr,
      4096, 1536, 512, 2);

  k_gru<<<64, 256, 0, stream>>>(
      (u16*)(ws + o_whhf), (u16*)(ws + o_whhb), b_hh_f, b_hh_b,
      (float*)(ws + o_xgf), (float*)(ws + o_xgb), (u16*)(ws + o_hbuf),
      out_states, (u16*)(ws + o_sbf),
      (unsigned*)(ws + o_bar), (unsigned*)(ws + o_bar) + 1);

  // m1 = clip(states @ att_w1^T), single-bf16 operands
  k_gemm<<<dim3(32, 2), 256, 0, stream>>>(
      (u16*)(ws + o_sbf), nullptr,
      (u16*)(ws + o_watt1), nullptr,
      nullptr, nullptr, (u16*)(ws + o_m1), nullptr,
      4096, 256, 1024, 1);

  k_alpha<<<64, 256, 0, stream>>>((u16*)(ws + o_m1), att_w2, out_actv, (float*)(ws + o_actv));
  k_context<<<256, 256, 0, stream>>>((float*)(ws + o_actv), out_states, out_ctx);
  k_final<<<64, 256, 0, stream>>>(out_ctx, lin_w, lin_b, out_probs);
}

// Round 3
// 1043.706 us; speedup vs baseline: 1.7034x; 1.7034x over previous
//
#include <hip/hip_runtime.h>

typedef unsigned short u16;
typedef unsigned long long u64t;
typedef __attribute__((ext_vector_type(8))) short bf16x8;
typedef __attribute__((ext_vector_type(4))) float f32x4;

__device__ __forceinline__ u16 f2bf(float f) {
  unsigned u = __float_as_uint(f);
  return (u16)((u + 0x7fffu + ((u >> 16) & 1u)) >> 16);
}
__device__ __forceinline__ float bf2f(u16 v) { return __uint_as_float(((unsigned)v) << 16); }
__device__ __forceinline__ float sigm(float x) { return 1.f / (1.f + __expf(-x)); }
__device__ __forceinline__ float tanh_(float x) {
  x = fminf(fmaxf(x, -15.f), 15.f);
  float e = __expf(2.f * x);
  return (e - 1.f) / (e + 1.f);
}

// ---------------- weight fp32 -> bf16 conversion (hi, optional lo residual) -------------
__global__ __launch_bounds__(256) void k_convert(
    const float* __restrict__ s0, const float* __restrict__ s1, const float* __restrict__ s2,
    const float* __restrict__ s3, const float* __restrict__ s4, const float* __restrict__ s5,
    u16* __restrict__ h0, u16* __restrict__ l0,
    u16* __restrict__ h1, u16* __restrict__ l1,
    u16* __restrict__ h2,
    u16* __restrict__ h3, u16* __restrict__ l3,
    u16* __restrict__ h4,
    u16* __restrict__ h5) {
  int blk = blockIdx.x;
  const float* s; u16 *dh, *dl; int rel;
  if (blk < 128)       { s = s0; dh = h0; dl = l0;      rel = blk; }
  else if (blk < 512)  { s = s1; dh = h1; dl = l1;      rel = blk - 128; }
  else if (blk < 896)  { s = s2; dh = h2; dl = nullptr; rel = blk - 512; }
  else if (blk < 1280) { s = s3; dh = h3; dl = l3;      rel = blk - 896; }
  else if (blk < 1664) { s = s4; dh = h4; dl = nullptr; rel = blk - 1280; }
  else                 { s = s5; dh = h5; dl = nullptr; rel = blk - 1664; }
  size_t i = (size_t)rel * 2048 + (size_t)threadIdx.x * 8;
  float v[8];
  *(f32x4*)v = *(const f32x4*)(s + i);
  *(f32x4*)(v + 4) = *(const f32x4*)(s + i + 4);
  u16 oh[8], ol[8];
#pragma unroll
  for (int j = 0; j < 8; j++) {
    oh[j] = f2bf(v[j]);
    ol[j] = f2bf(v[j] - bf2f(oh[j]));
  }
  uint4 pk;
  pk.x = (unsigned)oh[0] | ((unsigned)oh[1] << 16);
  pk.y = (unsigned)oh[2] | ((unsigned)oh[3] << 16);
  pk.z = (unsigned)oh[4] | ((unsigned)oh[5] << 16);
  pk.w = (unsigned)oh[6] | ((unsigned)oh[7] << 16);
  *(uint4*)(dh + i) = pk;
  if (dl) {
    uint4 pl;
    pl.x = (unsigned)ol[0] | ((unsigned)ol[1] << 16);
    pl.y = (unsigned)ol[2] | ((unsigned)ol[3] << 16);
    pl.z = (unsigned)ol[4] | ((unsigned)ol[5] << 16);
    pl.w = (unsigned)ol[6] | ((unsigned)ol[7] << 16);
    *(uint4*)(dl + i) = pl;
  }
}

// ---------------- fused conv + vec ----------------
__global__ __launch_bounds__(256) void k_convvec(
    const float* __restrict__ x, const float* __restrict__ cw,
    const float* __restrict__ cb, u16* __restrict__ vh, u16* __restrict__ vl) {
  __shared__ float lx[32 * 512];
  __shared__ float lcw[512];
  __shared__ float lconv[32];
  int bs = blockIdx.x;  // b*64+s
  const float* xp = x + (size_t)bs * 32 * 512;
  int t = threadIdx.x;
#pragma unroll
  for (int i = 0; i < 16; i++) {
    int idx = t + i * 256;
    ((float4*)lx)[idx] = ((const float4*)xp)[idx];
  }
  if (t < 128) ((float4*)lcw)[t] = ((const float4*)cw)[t];
  __syncthreads();
  int p = t >> 3, l = t & 7;
  float acc = 0.f;
#pragma unroll 8
  for (int j = 0; j < 64; j++) {
    int d = l + 8 * j;
    acc += lx[p * 512 + d] * lcw[d];
  }
  acc += __shfl_down(acc, 4);
  acc += __shfl_down(acc, 2);
  acc += __shfl_down(acc, 1);
  if (l == 0) lconv[p] = acc + cb[0];
  __syncthreads();
#pragma unroll
  for (int i = 0; i < 2; i++) {
    int d = t + i * 256;
    float v = 0.f;
#pragma unroll
    for (int pp = 0; pp < 32; pp++) v += lconv[pp] * lx[pp * 512 + d];
    u16 hb = f2bf(v);
    vh[(size_t)bs * 512 + d] = hb;
    vl[(size_t)bs * 512 + d] = f2bf(v - bf2f(hb));
  }
}

// ---------------- split-bf16 MFMA GEMM: C = act((Ah+Al)[M,K] @ (Wh+Wl)[N,K]^T + bias) ----
// flags: 1 = clip(-1,1), 2 = transpose output rows (m=b*64+s -> row s*64+b)
__global__ __launch_bounds__(256) void k_gemm(
    const u16* __restrict__ Ah, const u16* __restrict__ Al,
    const u16* __restrict__ Wh, const u16* __restrict__ Wl,
    const float* __restrict__ bias, float* __restrict__ outf,
    u16* __restrict__ obh, u16* __restrict__ obl,
    int M, int N, int K, int flags) {
  __shared__ u16 lAh[128 * 32];
  __shared__ u16 lAl[128 * 32];
  __shared__ u16 lWh[128 * 32];
  __shared__ u16 lWl[128 * 32];
  int m0 = blockIdx.x * 128, n0 = blockIdx.y * 128;
  int t = threadIdx.x;
  int wave = t >> 6, lane = t & 63;
  int wy = wave >> 1, wx = wave & 1;
  int q = lane >> 4, r16 = lane & 15;
  f32x4 acc[4][4];
#pragma unroll
  for (int mi = 0; mi < 4; mi++)
#pragma unroll
    for (int ni = 0; ni < 4; ni++) acc[mi][ni] = (f32x4){0.f, 0.f, 0.f, 0.f};

  for (int k0 = 0; k0 < K; k0 += 32) {
    __syncthreads();
#pragma unroll
    for (int i = 0; i < 2; i++) {
      int c = t + i * 256;
      int row = c >> 2, seg = c & 3;
      int lo = row * 32 + seg * 8;
      size_t ga = (size_t)(m0 + row) * K + k0 + seg * 8;
      size_t gw = (size_t)(n0 + row) * K + k0 + seg * 8;
      *(uint4*)(&lAh[lo]) = *(const uint4*)(&Ah[ga]);
      *(uint4*)(&lWh[lo]) = *(const uint4*)(&Wh[gw]);
      if (Al) *(uint4*)(&lAl[lo]) = *(const uint4*)(&Al[ga]);
      if (Wl) *(uint4*)(&lWl[lo]) = *(const uint4*)(&Wl[gw]);
    }
    __syncthreads();
    bf16x8 afh[4], bfh[4], afl[4], bfl[4];
#pragma unroll
    for (int mi = 0; mi < 4; mi++) afh[mi] = *(bf16x8*)(&lAh[(wy * 64 + mi * 16 + r16) * 32 + q * 8]);
#pragma unroll
    for (int ni = 0; ni < 4; ni++) bfh[ni] = *(bf16x8*)(&lWh[(wx * 64 + ni * 16 + r16) * 32 + q * 8]);
    if (Al) {
#pragma unroll
      for (int mi = 0; mi < 4; mi++) afl[mi] = *(bf16x8*)(&lAl[(wy * 64 + mi * 16 + r16) * 32 + q * 8]);
    }
    if (Wl) {
#pragma unroll
      for (int ni = 0; ni < 4; ni++) bfl[ni] = *(bf16x8*)(&lWl[(wx * 64 + ni * 16 + r16) * 32 + q * 8]);
    }
#pragma unroll
    for (int mi = 0; mi < 4; mi++)
#pragma unroll
      for (int ni = 0; ni < 4; ni++)
        acc[mi][ni] = __builtin_amdgcn_mfma_f32_16x16x32_bf16(afh[mi], bfh[ni], acc[mi][ni], 0, 0, 0);
    if (Al) {
#pragma unroll
      for (int mi = 0; mi < 4; mi++)
#pragma unroll
        for (int ni = 0; ni < 4; ni++)
          acc[mi][ni] = __builtin_amdgcn_mfma_f32_16x16x32_bf16(afl[mi], bfh[ni], acc[mi][ni], 0, 0, 0);
    }
    if (Wl) {
#pragma unroll
      for (int mi = 0; mi < 4; mi++)
#pragma unroll
        for (int ni = 0; ni < 4; ni++)
          acc[mi][ni] = __builtin_amdgcn_mfma_f32_16x16x32_bf16(afh[mi], bfl[ni], acc[mi][ni], 0, 0, 0);
    }
  }
#pragma unroll
  for (int mi = 0; mi < 4; mi++)
#pragma unroll
    for (int ni = 0; ni < 4; ni++)
#pragma unroll
      for (int reg = 0; reg < 4; reg++) {
        int m = m0 + wy * 64 + mi * 16 + q * 4 + reg;
        int n = n0 + wx * 64 + ni * 16 + r16;
        float v = acc[mi][ni][reg];
        if (bias) v += bias[n];
        if (flags & 1) v = fminf(fmaxf(v, -1.f), 1.f);
        int mr = (flags & 2) ? ((m & 63) * 64 + (m >> 6)) : m;
        size_t o = (size_t)mr * N + n;
        if (outf) outf[o] = v;
        if (obh) {
          u16 hb = f2bf(v);
          obh[o] = hb;
          if (obl) obl[o] = f2bf(v - bf2f(hb));
        }
      }
}

// ---------------- GRU recurrence ----------------
// 64 WGs: wg>>5 = dir, wg&31 = 16-row slice. w_hh slice in VGPR/AGPR MFMA fragments.
// h exchanged through L3 via relaxed agent-scope atomics (sc0 sc1 — L1/L2 bypass,
// NO fences => no per-step buffer_wbl2/inv, L2 stays warm for whh/xg).
// Barrier: per-direction 32-slot flag array; arrive = sc1 store after vmcnt(0) drain;
// wait = wave0 polls 32 flags lane-parallel. No RMW serialization.
__global__ __launch_bounds__(256, 1) void k_gru(
    const u16* __restrict__ whh_f, const u16* __restrict__ whh_b,
    const float* __restrict__ bhh_f, const float* __restrict__ bhh_b,
    const float* __restrict__ xg_f, const float* __restrict__ xg_b,
    u16* __restrict__ hbuf,            // [dir][2][64][512] bf16
    float* __restrict__ states_f32,    // d_out states region [b][s][1024]
    u16* __restrict__ states_bf,       // ws bf16 copy, same layout
    unsigned* __restrict__ flags0, unsigned* __restrict__ flags1) {
  int wg = blockIdx.x;
  int dir = wg >> 5;
  int slot = wg & 31;
  int r0 = slot * 16;
  int t = threadIdx.x, wave = t >> 6, lane = t & 63;
  int q = lane >> 4, r16 = lane & 15;
  const u16* whh = dir ? whh_b : whh_f;
  const float* bhh = dir ? bhh_b : bhh_f;
  const float* xg = dir ? xg_b : xg_f;
  unsigned* flags = dir ? flags1 : flags0;

  // persistent weight fragments: wA[g][kt] : A[m -> row r0+(lane&15) of gate g][k]
  bf16x8 wA[3][16];
#pragma unroll
  for (int g = 0; g < 3; g++)
#pragma unroll
    for (int kt = 0; kt < 16; kt++)
      wA[g][kt] = *(const bf16x8*)(&whh[(size_t)(g * 512 + r0 + r16) * 512 + kt * 32 + q * 8]);

  f32x4 bh[3];
#pragma unroll
  for (int g = 0; g < 3; g++) bh[g] = *(const f32x4*)(&bhh[g * 512 + r0 + q * 4]);

  float hreg[4] = {0.f, 0.f, 0.f, 0.f};
  int b = wave * 16 + r16;  // this lane's batch column
  int cur = 0;

  // prologue: xg for step 0
  {
    int s0i = dir ? 63 : 0;
    const float* xgp = xg + ((size_t)s0i * 64 + b) * 1536 + r0 + q * 4;
    hreg[0] = 0.f;  // keep
  }
  int sfirst = dir ? 63 : 0;
  const float* xgp0 = xg + ((size_t)sfirst * 64 + b) * 1536 + r0 + q * 4;
  f32x4 xr4 = *(const f32x4*)(xgp0);
  f32x4 xz4 = *(const f32x4*)(xgp0 + 512);
  f32x4 xn4 = *(const f32x4*)(xgp0 + 1024);

  for (int tt = 0; tt < 64; tt++) {
    int s = dir ? (63 - tt) : tt;

    // coherent h load: 32 x 8B relaxed agent atomics (sc0 sc1), all in flight
    const u64t* hc = (const u64t*)(hbuf + ((size_t)(dir * 2 + cur) * 64 + b) * 512);
    u64t hu[32];
#pragma unroll
    for (int kt = 0; kt < 16; kt++) {
      hu[2 * kt]     = __hip_atomic_load(hc + kt * 8 + q * 2,     __ATOMIC_RELAXED, __HIP_MEMORY_SCOPE_AGENT);
      hu[2 * kt + 1] = __hip_atomic_load(hc + kt * 8 + q * 2 + 1, __ATOMIC_RELAXED, __HIP_MEMORY_SCOPE_AGENT);
    }

    // prefetch next step's xg (h-independent; overlaps MFMA + barrier)
    f32x4 nxr, nxz, nxn;
    if (tt < 63) {
      int sn = dir ? (62 - tt) : (tt + 1);
      const float* xgn = xg + ((size_t)sn * 64 + b) * 1536 + r0 + q * 4;
      nxr = *(const f32x4*)(xgn);
      nxz = *(const f32x4*)(xgn + 512);
      nxn = *(const f32x4*)(xgn + 1024);
    }

    f32x4 acc[3];
#pragma unroll
    for (int g = 0; g < 3; g++) acc[g] = (f32x4){0.f, 0.f, 0.f, 0.f};
#pragma unroll
    for (int kt = 0; kt < 16; kt++) {
      union { u64t u[2]; bf16x8 v; } cv;
      cv.u[0] = hu[2 * kt];
      cv.u[1] = hu[2 * kt + 1];
#pragma unroll
      for (int g = 0; g < 3; g++)
        acc[g] = __builtin_amdgcn_mfma_f32_16x16x32_bf16(wA[g][kt], cv.v, acc[g], 0, 0, 0);
    }

    float hn4[4];
    u16 hnb[4];
#pragma unroll
    for (int reg = 0; reg < 4; reg++) {
      float hgr = acc[0][reg] + bh[0][reg];
      float hgz = acc[1][reg] + bh[1][reg];
      float hgn = acc[2][reg] + bh[2][reg];
      float rr = sigm(xr4[reg] + hgr);
      float zz = sigm(xz4[reg] + hgz);
      float nn = tanh_(xn4[reg] + rr * hgn);
      float hv = (1.f - zz) * nn + zz * hreg[reg];
      hreg[reg] = hv;
      hn4[reg] = hv;
      hnb[reg] = f2bf(hv);
    }
    int R = r0 + q * 4;
    float4 st; st.x = hn4[0]; st.y = hn4[1]; st.z = hn4[2]; st.w = hn4[3];
    *(float4*)(states_f32 + ((size_t)(b * 64 + s) * 1024 + dir * 512 + R)) = st;
    uint2 pk;
    pk.x = (unsigned)hnb[0] | ((unsigned)hnb[1] << 16);
    pk.y = (unsigned)hnb[2] | ((unsigned)hnb[3] << 16);
    *(uint2*)(states_bf + ((size_t)(b * 64 + s) * 1024 + dir * 512 + R)) = pk;
    u64t hpk = (u64t)pk.x | ((u64t)pk.y << 32);
    __hip_atomic_store((u64t*)(hbuf + ((size_t)(dir * 2 + (cur ^ 1)) * 64 + b) * 512 + R),
                       hpk, __ATOMIC_RELAXED, __HIP_MEMORY_SCOPE_AGENT);

    // ---- flag barrier (per direction) ----
    asm volatile("s_waitcnt vmcnt(0)" ::: "memory");  // h stores visible at L3
    __syncthreads();                                   // all 4 waves drained
    if (t == 0)
      __hip_atomic_store(&flags[slot], (unsigned)(tt + 1), __ATOMIC_RELAXED, __HIP_MEMORY_SCOPE_AGENT);
    if (wave == 0) {
      unsigned tgt = (unsigned)(tt + 1);
      for (;;) {
        unsigned f = (lane < 32)
            ? __hip_atomic_load(&flags[lane], __ATOMIC_RELAXED, __HIP_MEMORY_SCOPE_AGENT)
            : tgt;
        if (__all((int)(f >= tgt))) break;
        __builtin_amdgcn_s_sleep(1);
      }
    }
    __syncthreads();

    cur ^= 1;
    xr4 = nxr; xz4 = nxz; xn4 = nxn;
  }
}

// ---------------- alpha = m1 @ att_w2^T ; softmax over S ----------------
__global__ __launch_bounds__(256) void k_alpha(
    const u16* __restrict__ m1, const float* __restrict__ w2,
    float* __restrict__ actv_out, float* __restrict__ actv_ws) {
  __shared__ float lw2[4 * 256];
  __shared__ float lal[256];
  __shared__ float red[8];
  int bb = blockIdx.x, t = threadIdx.x;
  for (int i = t; i < 1024; i += 256) lw2[i] = w2[i];
  __syncthreads();
  int s = t >> 2, h = t & 3;
  const u16* mp = m1 + ((size_t)bb * 64 + s) * 256;
  float a = 0.f;
  for (int c = 0; c < 256; c += 4) {
    ushort4 v = *(const ushort4*)(mp + c);
    a += bf2f(v.x) * lw2[h * 256 + c] + bf2f(v.y) * lw2[h * 256 + c + 1] +
         bf2f(v.z) * lw2[h * 256 + c + 2] + bf2f(v.w) * lw2[h * 256 + c + 3];
  }
  lal[s * 4 + h] = a;
  __syncthreads();
  if (t < 4) {
    float mx = -1e30f;
    for (int ss = 0; ss < 64; ss++) mx = fmaxf(mx, lal[ss * 4 + t]);
    float sm = 0.f;
    for (int ss = 0; ss < 64; ss++) sm += __expf(lal[ss * 4 + t] - mx);
    red[t] = mx; red[4 + t] = sm;
  }
  __syncthreads();
  float val = __expf(lal[s * 4 + h] - red[h]) / red[4 + h];
  int o = bb * 256 + h * 64 + s;
  actv_out[o] = val;
  actv_ws[o] = val;
}

// ---------------- context[b,h,:] = sum_s actv[b,h,s] * states[b,s,:] ----------------
__global__ __launch_bounds__(256) void k_context(
    const float* __restrict__ actv, const float* __restrict__ states, float* __restrict__ ctx) {
  __shared__ float la[64];
  int bb = blockIdx.x >> 2, h = blockIdx.x & 3, t = threadIdx.x;
  if (t < 64) la[t] = actv[bb * 256 + h * 64 + t];
  __syncthreads();
  const float* sp = states + (size_t)bb * 65536 + t * 4;
  f32x4 acc = (f32x4){0.f, 0.f, 0.f, 0.f};
  for (int s = 0; s < 64; s++) {
    f32x4 v = *(const f32x4*)(sp + (size_t)s * 1024);
    float a = la[s];
    acc += a * v;
  }
  *(f32x4*)(ctx + (size_t)bb * 4096 + h * 1024 + t * 4) = acc;
}

// ---------------- out = softmax(context @ lin_w^T + lin_b) ----------------
__global__ __launch_bounds__(256) void k_final(
    const float* __restrict__ ctx, const float* __restrict__ lw,
    const float* __restrict__ lb, float* __restrict__ out) {
  __shared__ float lctx[4096];
  __shared__ float lred[256];
  __shared__ float lout[16];
  int bb = blockIdx.x, t = threadIdx.x;
#pragma unroll
  for (int i = 0; i < 4; i++)
    ((float4*)lctx)[t + i * 256] = ((const float4*)(ctx + (size_t)bb * 4096))[t + i * 256];
  __syncthreads();
  int o = t >> 4, j = t & 15;
  const float* wp = lw + (size_t)o * 4096 + j * 256;
  const float* cp = lctx + j * 256;
  float a = 0.f;
  for (int c = 0; c < 256; c++) a += cp[c] * wp[c];
  lred[t] = a;
  __syncthreads();
  if (t < 16) {
    float v = lb[t];
    for (int jj = 0; jj < 16; jj++) v += lred[t * 16 + jj];
    lout[t] = v;
  }
  __syncthreads();
  if (t == 0) {
    float mx = -1e30f;
    for (int i = 0; i < 16; i++) mx = fmaxf(mx, lout[i]);
    float sm = 0.f;
    for (int i = 0; i < 16; i++) { float e = __expf(lout[i] - mx); lout[i] = e; sm += e; }
    float inv = 1.f / sm;
    for (int i = 0; i < 16; i++) out[bb * 16 + i] = lout[i] * inv;
  }
}

// ---------------- launch ----------------
extern "C" void kernel_launch(void* const* d_in, const int* in_sizes, int n_in,
                              void* d_out, int out_size, void* d_ws, size_t ws_size,
                              hipStream_t stream) {
  const float* x      = (const float*)d_in[0];
  const float* conv_w = (const float*)d_in[2];
  const float* conv_b = (const float*)d_in[3];
  const float* w_embed= (const float*)d_in[4];
  const float* w_ih_f = (const float*)d_in[5];
  const float* w_hh_f = (const float*)d_in[6];
  const float* b_ih_f = (const float*)d_in[7];
  const float* b_hh_f = (const float*)d_in[8];
  const float* w_ih_b = (const float*)d_in[9];
  const float* w_hh_b = (const float*)d_in[10];
  const float* b_ih_b = (const float*)d_in[11];
  const float* b_hh_b = (const float*)d_in[12];
  const float* att_w1 = (const float*)d_in[13];
  const float* att_w2 = (const float*)d_in[14];
  const float* lin_w  = (const float*)d_in[15];
  const float* lin_b  = (const float*)d_in[16];

  char* ws = (char*)d_ws;
  // ws layout (bytes); later-phase arrays alias dead earlier-phase regions
  const size_t o_bar    = 0;          // flags0 @0 (128B), flags1 @512 (128B)
  const size_t o_hbuf   = 1024;       // 524288
  const size_t o_wembh  = 525312;     // 524288
  const size_t o_wembl  = 1049600;    // 524288
  const size_t o_wihfh  = 1573888;    // 1572864
  const size_t o_wihfl  = 3146752;    // 1572864
  const size_t o_whhf   = 4719616;    // 1572864
  const size_t o_wihbh  = 6292480;    // 1572864
  const size_t o_wihbl  = 7865344;    // 1572864
  const size_t o_whhb   = 9438208;    // 1572864
  const size_t o_watt1  = 11011072;   // 524288
  const size_t o_embh   = 11535360;   // 4194304 (dead after xg GEMMs)
  const size_t o_embl   = 15729664;   // 4194304 (dead after xg GEMMs)
  const size_t o_vech   = 19923968;   // 4194304 (dead after emb GEMM)
  const size_t o_vecl   = 24118272;   // 4194304 (dead after emb GEMM)
  const size_t o_xgf    = 19923968;   // 25165824 (aliases vec; dead after k_gru)
  const size_t o_xgb    = 45089792;   // 25165824
  const size_t o_sbf    = 11535360;   // 8388608 (aliases emb; written by k_gru)
  const size_t o_m1     = 19923968;   // 2097152 (aliases xgf head; after k_gru)
  const size_t o_actv   = 22021120;   // 65536

  float* out_probs  = (float*)d_out;            // [64,16]
  float* out_states = out_probs + 1024;         // [64,64,1024]
  float* out_ctx    = out_probs + 4195328;      // [64,4096]
  float* out_actv   = out_probs + 4457472;      // [64,4,64]

  // zero flags + h buffers (ws is re-poisoned to 0xAA before every timed launch)
  hipMemsetAsync(ws + o_bar, 0, 525312, stream);

  k_convert<<<1792, 256, 0, stream>>>(
      w_embed, w_ih_f, w_hh_f, w_ih_b, w_hh_b, att_w1,
      (u16*)(ws + o_wembh), (u16*)(ws + o_wembl),
      (u16*)(ws + o_wihfh), (u16*)(ws + o_wihfl),
      (u16*)(ws + o_whhf),
      (u16*)(ws + o_wihbh), (u16*)(ws + o_wihbl),
      (u16*)(ws + o_whhb),
      (u16*)(ws + o_watt1));

  k_convvec<<<4096, 256, 0, stream>>>(x, conv_w, conv_b,
                                      (u16*)(ws + o_vech), (u16*)(ws + o_vecl));

  // emb = clip(vec @ w_embed^T), split-bf16 both operands, output hi/lo
  k_gemm<<<dim3(32, 4), 256, 0, stream>>>(
      (u16*)(ws + o_vech), (u16*)(ws + o_vecl),
      (u16*)(ws + o_wembh), (u16*)(ws + o_wembl),
      nullptr, nullptr, (u16*)(ws + o_embh), (u16*)(ws + o_embl),
      4096, 512, 512, 1);

  // xg = emb @ w_ih^T + b_ih, split-bf16, stored [s*64+b][1536] fp32
  k_gemm<<<dim3(32, 12), 256, 0, stream>>>(
      (u16*)(ws + o_embh), (u16*)(ws + o_embl),
      (u16*)(ws + o_wihfh), (u16*)(ws + o_wihfl),
      b_ih_f, (float*)(ws + o_xgf), nullptr, nullptr,
      4096, 1536, 512, 2);
  k_gemm<<<dim3(32, 12), 256, 0, stream>>>(
      (u16*)(ws + o_embh), (u16*)(ws + o_embl),
      (u16*)(ws + o_wihbh), (u16*)(ws + o_wihbl),
      b_ih_b, (float*)(ws + o_xgb), nullptr, nullptr,
      4096, 1536, 512, 2);

  k_gru<<<64, 256, 0, stream>>>(
      (u16*)(ws + o_whhf), (u16*)(ws + o_whhb), b_hh_f, b_hh_b,
      (float*)(ws + o_xgf), (float*)(ws + o_xgb), (u16*)(ws + o_hbuf),
      out_states, (u16*)(ws + o_sbf),
      (unsigned*)(ws + o_bar), (unsigned*)(ws + o_bar + 512));

  // m1 = clip(states @ att_w1^T), single-bf16 operands
  k_gemm<<<dim3(32, 2), 256, 0, stream>>>(
      (u16*)(ws + o_sbf), nullptr,
      (u16*)(ws + o_watt1), nullptr,
      nullptr, nullptr, (u16*)(ws + o_m1), nullptr,
      4096, 256, 1024, 1);

  k_alpha<<<64, 256, 0, stream>>>((u16*)(ws + o_m1), att_w2, out_actv, (float*)(ws + o_actv));
  k_context<<<256, 256, 0, stream>>>((float*)(ws + o_actv), out_states, out_ctx);
  k_final<<<64, 256, 0, stream>>>(out_ctx, lin_w, lin_b, out_probs);
}